// Round 1
// baseline (810.976 us; speedup 1.0000x reference)
//
#include <hip/hip_runtime.h>
#include <stdint.h>

// Problem constants (B=4, S=4096, D=2048, H=16, G=4, hd=128)
#define M_DIM 16384   // B*S tokens
#define D_DIM 2048
#define HEADS 16
#define GROUPS 4
#define HDIM 128

typedef __attribute__((ext_vector_type(8))) short bf16x8;
typedef __attribute__((ext_vector_type(4))) float f32x4;

__device__ __forceinline__ unsigned short f2bf(float f) {
  union { float f; uint32_t u; } c; c.f = f;
  uint32_t u = c.u;
  u += 0x7FFFu + ((u >> 16) & 1u);   // round-to-nearest-even
  return (unsigned short)(u >> 16);
}
__device__ __forceinline__ float bf2f(unsigned short h) {
  union { float f; uint32_t u; } c; c.u = ((uint32_t)h) << 16;
  return c.f;
}

__device__ __forceinline__ void gload_lds16(const unsigned short* g, unsigned short* l) {
  __builtin_amdgcn_global_load_lds(
      (const __attribute__((address_space(1))) void*)g,
      (__attribute__((address_space(3))) void*)l,
      16, 0, 0);
}

// ---------------- x (fp32) -> bf16 ----------------
__global__ __launch_bounds__(256) void cvt_x_kernel(const float4* __restrict__ in,
                                                    unsigned short* __restrict__ out,
                                                    int n4) {
  int i = blockIdx.x * blockDim.x + threadIdx.x;
  int stride = gridDim.x * blockDim.x;
  for (; i < n4; i += stride) {
    float4 v = in[i];
    ushort4 o;
    o.x = f2bf(v.x); o.y = f2bf(v.y); o.z = f2bf(v.z); o.w = f2bf(v.w);
    ((ushort4*)out)[i] = o;
  }
}

// ---------------- W (fp32, [K][N]) -> W^T (bf16, [N][K]) ----------------
__global__ __launch_bounds__(256) void cvt_wt_kernel(const float* __restrict__ W,
                                                     unsigned short* __restrict__ Wt) {
  __shared__ float tile[32][33];
  const int tx = threadIdx.x, ty = threadIdx.y;   // 32 x 8
  const int n0 = blockIdx.x * 32, k0 = blockIdx.y * 32;
  #pragma unroll
  for (int i = 0; i < 4; ++i)
    tile[ty + i * 8][tx] = W[(size_t)(k0 + ty + i * 8) * D_DIM + n0 + tx];
  __syncthreads();
  #pragma unroll
  for (int i = 0; i < 4; ++i)
    Wt[(size_t)(n0 + ty + i * 8) * D_DIM + k0 + tx] = f2bf(tile[tx][ty + i * 8]);
}

// ---------------- bf16 GEMM: C = A[M][K] @ Bt[N][K]^T (+bias) ----------------
// 128x128 tile, BK=32, 256 threads = 4 waves (2x2), each wave 64x64 = 4x4 mfma frags.
// QKV=true : Ntot=6144 (q|k|v planes), writes bf16 to out[plane][M][2048] with per-plane bias
// QKV=false: Ntot=2048, writes fp32 to out[M][2048] + bias0
template<bool QKV>
__global__ __launch_bounds__(256) void gemm_bt_kernel(
    const unsigned short* __restrict__ A,
    const unsigned short* __restrict__ Bt,
    const float* __restrict__ bias0,
    const float* __restrict__ bias1,
    const float* __restrict__ bias2,
    void* __restrict__ outp) {
  constexpr int K = 2048;
  __shared__ __align__(16) unsigned short As[128 * 32];
  __shared__ __align__(16) unsigned short Bs[128 * 32];

  const int tid = threadIdx.x;
  const int wave = tid >> 6;
  const int lane = tid & 63;
  const int bm = blockIdx.x * 128;
  const int bn = blockIdx.y * 128;
  const int wm = wave >> 1;
  const int wn = wave & 1;
  const int lr = lane & 15;
  const int lk = (lane >> 4) * 8;

  f32x4 acc[4][4];
  #pragma unroll
  for (int m = 0; m < 4; ++m)
    #pragma unroll
    for (int n = 0; n < 4; ++n)
      acc[m][n] = (f32x4){0.f, 0.f, 0.f, 0.f};

  const unsigned short* Ag = A + (size_t)bm * K;
  const unsigned short* Bg = Bt + (size_t)bn * K;

  // staging: 512 chunks of 16B per tile; chunk c -> row c/4, k-offset (c&3)*8
  const int c0 = wave * 64 + lane;
  const int c1 = 256 + c0;

  for (int kt = 0; kt < K; kt += 32) {
    gload_lds16(Ag + (size_t)(c0 >> 2) * K + kt + (c0 & 3) * 8, &As[c0 * 8]);
    gload_lds16(Ag + (size_t)(c1 >> 2) * K + kt + (c1 & 3) * 8, &As[c1 * 8]);
    gload_lds16(Bg + (size_t)(c0 >> 2) * K + kt + (c0 & 3) * 8, &Bs[c0 * 8]);
    gload_lds16(Bg + (size_t)(c1 >> 2) * K + kt + (c1 & 3) * 8, &Bs[c1 * 8]);
    __syncthreads();

    bf16x8 af[4], bfr[4];
    #pragma unroll
    for (int m = 0; m < 4; ++m)
      af[m] = *(const bf16x8*)&As[(wm * 64 + m * 16 + lr) * 32 + lk];
    #pragma unroll
    for (int n = 0; n < 4; ++n)
      bfr[n] = *(const bf16x8*)&Bs[(wn * 64 + n * 16 + lr) * 32 + lk];
    #pragma unroll
    for (int m = 0; m < 4; ++m)
      #pragma unroll
      for (int n = 0; n < 4; ++n)
        acc[m][n] = __builtin_amdgcn_mfma_f32_16x16x32_bf16(af[m], bfr[n], acc[m][n], 0, 0, 0);
    __syncthreads();
  }

  // epilogue: C/D layout col=lane&15, row=(lane>>4)*4+e  [m89/m91 verified]
  const int rbase = bm + wm * 64 + (lane >> 4) * 4;
  const int cbase = bn + wn * 64 + lr;
  if constexpr (QKV) {
    const int plane = bn >> 11;   // block fully inside one of q/k/v
    const float* bias = plane == 0 ? bias0 : (plane == 1 ? bias1 : bias2);
    unsigned short* out = (unsigned short*)outp + (size_t)plane * M_DIM * D_DIM;
    #pragma unroll
    for (int n = 0; n < 4; ++n) {
      const int cp = (cbase + n * 16) & (D_DIM - 1);
      const float bv = bias[cp];
      #pragma unroll
      for (int m = 0; m < 4; ++m)
        #pragma unroll
        for (int e = 0; e < 4; ++e) {
          const int row = rbase + m * 16 + e;
          out[(size_t)row * D_DIM + cp] = f2bf(acc[m][n][e] + bv);
        }
    }
  } else {
    float* out = (float*)outp;
    #pragma unroll
    for (int n = 0; n < 4; ++n) {
      const int col = cbase + n * 16;
      const float bv = bias0[col];
      #pragma unroll
      for (int m = 0; m < 4; ++m)
        #pragma unroll
        for (int e = 0; e < 4; ++e) {
          const int row = rbase + m * 16 + e;
          out[(size_t)row * D_DIM + col] = acc[m][n][e] + bv;
        }
    }
  }
}

// ---------------- per-token head attention ----------------
// 1 wave per token. lane: ih = lane>>2 (new head), qd = lane&3 (32-wide d-quarter).
// GQA perm: q_new[h] = q_old[(h%4)*4 + h/4].
__global__ __launch_bounds__(256) void attn_kernel(const unsigned short* __restrict__ qkv,
                                                   unsigned short* __restrict__ attnb) {
  __shared__ __align__(16) unsigned short kv_s[4][2][HEADS * HDIM];  // 32 KB
  const int tid = threadIdx.x;
  const int wave = tid >> 6;
  const int lane = tid & 63;
  const int t = blockIdx.x * 4 + wave;
  const size_t MD = (size_t)M_DIM * D_DIM;

  // stage this token's K and V into LDS (2048 bf16 each)
  const bf16x8* kg = (const bf16x8*)(qkv + MD + (size_t)t * D_DIM);
  const bf16x8* vg = (const bf16x8*)(qkv + 2 * MD + (size_t)t * D_DIM);
  bf16x8* ks = (bf16x8*)&kv_s[wave][0][0];
  bf16x8* vs = (bf16x8*)&kv_s[wave][1][0];
  #pragma unroll
  for (int i = 0; i < 4; ++i) {
    ks[i * 64 + lane] = kg[i * 64 + lane];
    vs[i * 64 + lane] = vg[i * 64 + lane];
  }

  // load q with head permutation (32 elems per lane)
  const int ih = lane >> 2;
  const int qd = lane & 3;
  const int hsrc = (ih & 3) * 4 + (ih >> 2);
  const unsigned short* qg = qkv + (size_t)t * D_DIM + hsrc * HDIM + qd * 32;
  float qreg[32];
  #pragma unroll
  for (int c = 0; c < 4; ++c) {
    bf16x8 q8 = ((const bf16x8*)qg)[c];
    #pragma unroll
    for (int e = 0; e < 8; ++e) qreg[c * 8 + e] = bf2f((unsigned short)q8[e]);
  }

  __syncthreads();

  // scores[ih][j], each lane owns a 32-wide K-slice, reduce over 4 lanes
  float s[16];
  #pragma unroll
  for (int j = 0; j < 16; ++j) {
    float acc = 0.f;
    const bf16x8* kp = (const bf16x8*)&kv_s[wave][0][j * HDIM + qd * 32];
    #pragma unroll
    for (int c = 0; c < 4; ++c) {
      bf16x8 k8 = kp[c];
      #pragma unroll
      for (int e = 0; e < 8; ++e) acc = fmaf(qreg[c * 8 + e], bf2f((unsigned short)k8[e]), acc);
    }
    acc += __shfl_xor(acc, 1);
    acc += __shfl_xor(acc, 2);
    s[j] = acc * 0.08838834764831845f;  // 1/sqrt(128)
  }

  // softmax over j (replicated across the 4 lanes of a head — fine)
  float mx = s[0];
  #pragma unroll
  for (int j = 1; j < 16; ++j) mx = fmaxf(mx, s[j]);
  float sum = 0.f;
  #pragma unroll
  for (int j = 0; j < 16; ++j) { s[j] = __expf(s[j] - mx); sum += s[j]; }
  const float inv = 1.f / sum;

  // attn[ih][myslice] = sum_j p[j] * v[j][myslice]
  float o[32];
  #pragma unroll
  for (int c = 0; c < 32; ++c) o[c] = 0.f;
  #pragma unroll
  for (int j = 0; j < 16; ++j) {
    const float p = s[j] * inv;
    const bf16x8* vp = (const bf16x8*)&kv_s[wave][1][j * HDIM + qd * 32];
    #pragma unroll
    for (int c = 0; c < 4; ++c) {
      bf16x8 v8 = vp[c];
      #pragma unroll
      for (int e = 0; e < 8; ++e) o[c * 8 + e] = fmaf(p, bf2f((unsigned short)v8[e]), o[c * 8 + e]);
    }
  }

  unsigned short* op = attnb + (size_t)t * D_DIM + ih * HDIM + qd * 32;
  #pragma unroll
  for (int c = 0; c < 4; ++c) {
    bf16x8 ov;
    #pragma unroll
    for (int e = 0; e < 8; ++e) ov[e] = (short)f2bf(o[c * 8 + e]);
    ((bf16x8*)op)[c] = ov;
  }
}

extern "C" void kernel_launch(void* const* d_in, const int* in_sizes, int n_in,
                              void* d_out, int out_size, void* d_ws, size_t ws_size,
                              hipStream_t stream) {
  const float* x  = (const float*)d_in[0];
  const float* Wq = (const float*)d_in[1];
  const float* bq = (const float*)d_in[2];
  const float* Wk = (const float*)d_in[3];
  const float* bk = (const float*)d_in[4];
  const float* Wv = (const float*)d_in[5];
  const float* bv = (const float*)d_in[6];
  const float* Wo = (const float*)d_in[7];
  const float* bo = (const float*)d_in[8];

  const size_t MD = (size_t)M_DIM * D_DIM;   // 33,554,432 elems
  const size_t DD = (size_t)D_DIM * D_DIM;   //  4,194,304 elems

  // ws layout (bf16 elems): [xb/attn: MD][Wt: 4*DD][qkv: 3*MD]  = ~302 MB
  unsigned short* xb   = (unsigned short*)d_ws;
  unsigned short* Wt   = xb + MD;
  unsigned short* qkvb = Wt + 4 * DD;
  const size_t need_bytes = (MD + 4 * DD + 3 * MD) * sizeof(unsigned short);
  if (ws_size < need_bytes) return;  // workspace too small — fail loudly via mismatch

  // 1) x -> bf16
  cvt_x_kernel<<<2048, 256, 0, stream>>>((const float4*)x, xb, (int)(MD / 4));

  // 2) weights -> bf16 transposed [N][K]
  dim3 tb(32, 8), tg(64, 64);
  cvt_wt_kernel<<<tg, tb, 0, stream>>>(Wq, Wt + 0 * DD);
  cvt_wt_kernel<<<tg, tb, 0, stream>>>(Wk, Wt + 1 * DD);
  cvt_wt_kernel<<<tg, tb, 0, stream>>>(Wv, Wt + 2 * DD);
  cvt_wt_kernel<<<tg, tb, 0, stream>>>(Wo, Wt + 3 * DD);

  // 3) fused QKV GEMM: [16384,2048] @ [2048,6144] -> q|k|v bf16 planes
  gemm_bt_kernel<true><<<dim3(128, 48), 256, 0, stream>>>(xb, Wt, bq, bk, bv, qkvb);

  // 4) per-token head attention -> attn bf16 (reuses xb)
  attn_kernel<<<4096, 256, 0, stream>>>(qkvb, xb);

  // 5) output GEMM: attn @ Wo + bo -> fp32
  gemm_bt_kernel<false><<<dim3(128, 16), 256, 0, stream>>>(xb, Wt + 3 * DD, bo, nullptr, nullptr, d_out);
}

// Round 2
// 640.453 us; speedup vs baseline: 1.2663x; 1.2663x over previous
//
#include <hip/hip_runtime.h>
#include <stdint.h>

// Problem constants (B=4, S=4096, D=2048, H=16, G=4, hd=128)
#define M_DIM 16384   // B*S tokens
#define D_DIM 2048
#define HEADS 16
#define HDIM 128

typedef __attribute__((ext_vector_type(8))) short bf16x8;
typedef __attribute__((ext_vector_type(4))) float f32x4;

__device__ __forceinline__ unsigned short f2bf(float f) {
  union { float f; uint32_t u; } c; c.f = f;
  uint32_t u = c.u;
  u += 0x7FFFu + ((u >> 16) & 1u);   // round-to-nearest-even
  return (unsigned short)(u >> 16);
}
__device__ __forceinline__ float bf2f(unsigned short h) {
  union { float f; uint32_t u; } c; c.u = ((uint32_t)h) << 16;
  return c.f;
}

__device__ __forceinline__ void gload_lds16(const unsigned short* g, unsigned short* l) {
  __builtin_amdgcn_global_load_lds(
      (const __attribute__((address_space(1))) void*)g,
      (__attribute__((address_space(3))) void*)l,
      16, 0, 0);
}

// ---------------- x (fp32) -> bf16 ----------------
__global__ __launch_bounds__(256) void cvt_x_kernel(const float4* __restrict__ in,
                                                    unsigned short* __restrict__ out,
                                                    int n4) {
  int i = blockIdx.x * blockDim.x + threadIdx.x;
  int stride = gridDim.x * blockDim.x;
  for (; i < n4; i += stride) {
    float4 v = in[i];
    ushort4 o;
    o.x = f2bf(v.x); o.y = f2bf(v.y); o.z = f2bf(v.z); o.w = f2bf(v.w);
    ((ushort4*)out)[i] = o;
  }
}

// ---------------- W (fp32, [K][N]) -> W^T (bf16, [N][K]) ----------------
__global__ __launch_bounds__(256) void cvt_wt_kernel(const float* __restrict__ W,
                                                     unsigned short* __restrict__ Wt) {
  __shared__ float tile[32][33];
  const int tx = threadIdx.x, ty = threadIdx.y;   // 32 x 8
  const int n0 = blockIdx.x * 32, k0 = blockIdx.y * 32;
  #pragma unroll
  for (int i = 0; i < 4; ++i)
    tile[ty + i * 8][tx] = W[(size_t)(k0 + ty + i * 8) * D_DIM + n0 + tx];
  __syncthreads();
  #pragma unroll
  for (int i = 0; i < 4; ++i)
    Wt[(size_t)(n0 + ty + i * 8) * D_DIM + k0 + tx] = f2bf(tile[tx][ty + i * 8]);
}

// ================= 256x256 8-phase bf16 GEMM (m201-template port) ==========
// C = A[M][K] @ Bt[N][K]^T (+bias). 512 thr = 8 waves (2M x 4N), BK=64,
// LDS 128KB double-buffered, st-swizzled (XOR (row&7)<<4, pre-swizzled src).
// Counted vmcnt(4) at phases 4/8 only; every prefetch lands >=1 phase after
// its target region's last read (race-free by barrier+lgkmcnt discipline).

#define SYNC_MID()                                          \
  do {                                                      \
    __builtin_amdgcn_sched_barrier(0);                      \
    __builtin_amdgcn_s_barrier();                           \
    asm volatile("s_waitcnt lgkmcnt(0)" ::: "memory");      \
    __builtin_amdgcn_sched_barrier(0);                      \
  } while (0)

#define SYNC_END()                                          \
  do {                                                      \
    __builtin_amdgcn_sched_barrier(0);                      \
    __builtin_amdgcn_s_barrier();                           \
    __builtin_amdgcn_sched_barrier(0);                      \
  } while (0)

#define READ_A(buf, mh, AF)                                               \
  do {                                                                    \
    const char* _ab = (const char*)&lds[buf][0][0];                       \
    _Pragma("unroll") for (int m = 0; m < 4; ++m) {                       \
      _Pragma("unroll") for (int kk = 0; kk < 2; ++kk) {                  \
        AF[m * 2 + kk] = *(const bf16x8*)(_ab +                           \
            (wm * 128 + (mh) * 64 + m * 16 + fr) * 128 +                  \
            (((kk * 4 + lk8) ^ swz) << 4));                               \
      }                                                                   \
    }                                                                     \
  } while (0)

#define READ_B(buf, nh, BF)                                               \
  do {                                                                    \
    const char* _bb = (const char*)&lds[buf][1][0];                       \
    _Pragma("unroll") for (int n = 0; n < 2; ++n) {                       \
      _Pragma("unroll") for (int kk = 0; kk < 2; ++kk) {                  \
        BF[n * 2 + kk] = *(const bf16x8*)(_bb +                           \
            (wn * 64 + (nh) * 32 + n * 16 + fr) * 128 +                   \
            (((kk * 4 + lk8) ^ swz) << 4));                               \
      }                                                                   \
    }                                                                     \
  } while (0)

#define MFMA_Q(mh, nh, AF, BF)                                            \
  do {                                                                    \
    _Pragma("unroll") for (int m = 0; m < 4; ++m) {                       \
      _Pragma("unroll") for (int n = 0; n < 2; ++n) {                     \
        _Pragma("unroll") for (int kk = 0; kk < 2; ++kk) {                \
          acc[(mh) * 4 + m][(nh) * 2 + n] =                               \
              __builtin_amdgcn_mfma_f32_16x16x32_bf16(                    \
                  AF[m * 2 + kk], BF[n * 2 + kk],                         \
                  acc[(mh) * 4 + m][(nh) * 2 + n], 0, 0, 0);              \
        }                                                                 \
      }                                                                   \
    }                                                                     \
  } while (0)

template<bool QKV>
__global__ __launch_bounds__(512, 2) void gemm256_kernel(
    const unsigned short* __restrict__ A,
    const unsigned short* __restrict__ Bt,
    const float* __restrict__ bias0,
    const float* __restrict__ bias1,
    const float* __restrict__ bias2,
    void* __restrict__ outp) {
  constexpr int K = 2048;
  constexpr int NT = 32;                 // K / 64
  __shared__ __align__(16) unsigned short lds[2][2][16384];  // [buf][A/B], 128 KiB

  const int tid = threadIdx.x;
  const int wave = tid >> 6;
  const int lane = tid & 63;
  const int fr = lane & 15;
  const int lk8 = lane >> 4;             // 0..3
  const int wm = wave >> 2;              // 0..1
  const int wn = wave & 3;               // 0..3
  const int swz = fr & 7;                // read-side XOR (16B units)

  // T1: bijective XCD swizzle (nwg % 8 == 0 for both GEMMs)
  const int nwg = gridDim.x;
  const int orig = blockIdx.x;
  const int wg = (orig & 7) * (nwg >> 3) + (orig >> 3);
  const int mi = wg & 63;                // 64 M-blocks
  const int ni = wg >> 6;

  const unsigned short* Ag = A + (size_t)(mi * 256) * K;
  const unsigned short* Bg = Bt + (size_t)(ni * 256) * K;
  const int k8s = (lane & 7) ^ (lane >> 3);   // pre-swizzled source k-octet

  // stage one half-tile (128 rows x 64 k) : 2 x global_load_lds per thread
  auto stageA = [&](int tt, int half) {
    unsigned short* dst = &lds[tt & 1][0][0];
    #pragma unroll
    for (int j = 0; j < 2; ++j) {
      const int c = wave * 128 + j * 64 + lane;
      const int r = half * 128 + (c >> 3);
      gload_lds16(Ag + (size_t)r * K + tt * 64 + k8s * 8,
                  dst + (size_t)(half * 1024 + c) * 8);
    }
  };
  auto stageB = [&](int tt, int half) {
    unsigned short* dst = &lds[tt & 1][1][0];
    #pragma unroll
    for (int j = 0; j < 2; ++j) {
      const int c = wave * 128 + j * 64 + lane;
      const int r = half * 128 + (c >> 3);
      gload_lds16(Bg + (size_t)r * K + tt * 64 + k8s * 8,
                  dst + (size_t)(half * 1024 + c) * 8);
    }
  };

  f32x4 acc[8][4];
  #pragma unroll
  for (int m = 0; m < 8; ++m)
    #pragma unroll
    for (int n = 0; n < 4; ++n)
      acc[m][n] = (f32x4){0.f, 0.f, 0.f, 0.f};

  // prologue: tile0 fully + tile1 A-halves; drain to 4 loads (t1.Aa/Ab in flight)
  stageA(0, 0); stageA(0, 1); stageB(0, 0); stageB(0, 1);
  stageA(1, 0); stageA(1, 1);
  asm volatile("s_waitcnt vmcnt(4)" ::: "memory");
  __builtin_amdgcn_s_barrier();

  bf16x8 af0[8], af1[8], bf[4];
  #pragma unroll 1
  for (int t = 0; t < NT; t += 2) {
    // ---- K-tile t (buf 0); quadrant order (0,0)(1,0)(1,1)(0,1) ----
    // ph1
    READ_A(0, 0, af0); READ_B(0, 0, bf);
    stageB(t + 1, 0);
    SYNC_MID();
    __builtin_amdgcn_s_setprio(1); MFMA_Q(0, 0, af0, bf); __builtin_amdgcn_s_setprio(0);
    SYNC_END();
    // ph2
    READ_A(0, 1, af1);
    stageB(t + 1, 1);
    SYNC_MID();
    __builtin_amdgcn_s_setprio(1); MFMA_Q(1, 0, af1, bf); __builtin_amdgcn_s_setprio(0);
    SYNC_END();
    // ph3
    READ_B(0, 1, bf);
    if (t + 2 < NT) stageA(t + 2, 0);
    SYNC_MID();
    __builtin_amdgcn_s_setprio(1); MFMA_Q(1, 1, af1, bf); __builtin_amdgcn_s_setprio(0);
    SYNC_END();
    // ph4
    if (t + 2 < NT) stageA(t + 2, 1);
    SYNC_MID();
    __builtin_amdgcn_s_setprio(1); MFMA_Q(0, 1, af0, bf); __builtin_amdgcn_s_setprio(0);
    if (t + 2 < NT) { asm volatile("s_waitcnt vmcnt(4)" ::: "memory"); }
    else            { asm volatile("s_waitcnt vmcnt(0)" ::: "memory"); }
    SYNC_END();
    // ---- K-tile t+1 (buf 1) ----
    // ph5
    READ_A(1, 0, af0); READ_B(1, 0, bf);
    if (t + 2 < NT) stageB(t + 2, 0);
    SYNC_MID();
    __builtin_amdgcn_s_setprio(1); MFMA_Q(0, 0, af0, bf); __builtin_amdgcn_s_setprio(0);
    SYNC_END();
    // ph6
    READ_A(1, 1, af1);
    if (t + 2 < NT) stageB(t + 2, 1);
    SYNC_MID();
    __builtin_amdgcn_s_setprio(1); MFMA_Q(1, 0, af1, bf); __builtin_amdgcn_s_setprio(0);
    SYNC_END();
    // ph7
    READ_B(1, 1, bf);
    if (t + 3 < NT) stageA(t + 3, 0);
    SYNC_MID();
    __builtin_amdgcn_s_setprio(1); MFMA_Q(1, 1, af1, bf); __builtin_amdgcn_s_setprio(0);
    SYNC_END();
    // ph8
    if (t + 3 < NT) stageA(t + 3, 1);
    SYNC_MID();
    __builtin_amdgcn_s_setprio(1); MFMA_Q(0, 1, af0, bf); __builtin_amdgcn_s_setprio(0);
    if (t + 3 < NT) { asm volatile("s_waitcnt vmcnt(4)" ::: "memory"); }
    SYNC_END();
  }

  // epilogue: C/D layout col=lane&15, row=(lane>>4)*4+e
  const int rb = mi * 256 + wm * 128 + (lane >> 4) * 4;
  const int cb = ni * 256 + wn * 64 + fr;
  if constexpr (QKV) {
    const int plane = (ni * 256) >> 11;           // q/k/v plane, blocks never straddle
    const float* bias = plane == 0 ? bias0 : (plane == 1 ? bias1 : bias2);
    unsigned short* out = (unsigned short*)outp + (size_t)plane * M_DIM * D_DIM;
    #pragma unroll
    for (int n4 = 0; n4 < 4; ++n4) {
      const int col = (cb + n4 * 16) & (D_DIM - 1);
      const float bv = bias[col];
      #pragma unroll
      for (int m8 = 0; m8 < 8; ++m8)
        #pragma unroll
        for (int e = 0; e < 4; ++e)
          out[(size_t)(rb + m8 * 16 + e) * D_DIM + col] = f2bf(acc[m8][n4][e] + bv);
    }
  } else {
    float* out = (float*)outp;
    #pragma unroll
    for (int n4 = 0; n4 < 4; ++n4) {
      const int col = cb + n4 * 16;
      const float bv = bias0[col];
      #pragma unroll
      for (int m8 = 0; m8 < 8; ++m8)
        #pragma unroll
        for (int e = 0; e < 4; ++e)
          out[(size_t)(rb + m8 * 16 + e) * D_DIM + col] = acc[m8][n4][e] + bv;
    }
  }
}

// ---------------- per-token head attention ----------------
__global__ __launch_bounds__(256) void attn_kernel(const unsigned short* __restrict__ qkv,
                                                   unsigned short* __restrict__ attnb) {
  __shared__ __align__(16) unsigned short kv_s[4][2][HEADS * HDIM];  // 32 KB
  const int tid = threadIdx.x;
  const int wave = tid >> 6;
  const int lane = tid & 63;
  const int t = blockIdx.x * 4 + wave;
  const size_t MD = (size_t)M_DIM * D_DIM;

  const bf16x8* kg = (const bf16x8*)(qkv + MD + (size_t)t * D_DIM);
  const bf16x8* vg = (const bf16x8*)(qkv + 2 * MD + (size_t)t * D_DIM);
  bf16x8* ks = (bf16x8*)&kv_s[wave][0][0];
  bf16x8* vs = (bf16x8*)&kv_s[wave][1][0];
  #pragma unroll
  for (int i = 0; i < 4; ++i) {
    ks[i * 64 + lane] = kg[i * 64 + lane];
    vs[i * 64 + lane] = vg[i * 64 + lane];
  }

  const int ih = lane >> 2;
  const int qd = lane & 3;
  const int hsrc = (ih & 3) * 4 + (ih >> 2);   // GQA head permutation
  const unsigned short* qg = qkv + (size_t)t * D_DIM + hsrc * HDIM + qd * 32;
  float qreg[32];
  #pragma unroll
  for (int c = 0; c < 4; ++c) {
    bf16x8 q8 = ((const bf16x8*)qg)[c];
    #pragma unroll
    for (int e = 0; e < 8; ++e) qreg[c * 8 + e] = bf2f((unsigned short)q8[e]);
  }

  __syncthreads();

  float s[16];
  #pragma unroll
  for (int j = 0; j < 16; ++j) {
    float acc = 0.f;
    const bf16x8* kp = (const bf16x8*)&kv_s[wave][0][j * HDIM + qd * 32];
    #pragma unroll
    for (int c = 0; c < 4; ++c) {
      bf16x8 k8 = kp[c];
      #pragma unroll
      for (int e = 0; e < 8; ++e) acc = fmaf(qreg[c * 8 + e], bf2f((unsigned short)k8[e]), acc);
    }
    acc += __shfl_xor(acc, 1);
    acc += __shfl_xor(acc, 2);
    s[j] = acc * 0.08838834764831845f;  // 1/sqrt(128)
  }

  float mx = s[0];
  #pragma unroll
  for (int j = 1; j < 16; ++j) mx = fmaxf(mx, s[j]);
  float sum = 0.f;
  #pragma unroll
  for (int j = 0; j < 16; ++j) { s[j] = __expf(s[j] - mx); sum += s[j]; }
  const float inv = 1.f / sum;

  float o[32];
  #pragma unroll
  for (int c = 0; c < 32; ++c) o[c] = 0.f;
  #pragma unroll
  for (int j = 0; j < 16; ++j) {
    const float p = s[j] * inv;
    const bf16x8* vp = (const bf16x8*)&kv_s[wave][1][j * HDIM + qd * 32];
    #pragma unroll
    for (int c = 0; c < 4; ++c) {
      bf16x8 v8 = vp[c];
      #pragma unroll
      for (int e = 0; e < 8; ++e) o[c * 8 + e] = fmaf(p, bf2f((unsigned short)v8[e]), o[c * 8 + e]);
    }
  }

  unsigned short* op = attnb + (size_t)t * D_DIM + ih * HDIM + qd * 32;
  #pragma unroll
  for (int c = 0; c < 4; ++c) {
    bf16x8 ov;
    #pragma unroll
    for (int e = 0; e < 8; ++e) ov[e] = (short)f2bf(o[c * 8 + e]);
    ((bf16x8*)op)[c] = ov;
  }
}

extern "C" void kernel_launch(void* const* d_in, const int* in_sizes, int n_in,
                              void* d_out, int out_size, void* d_ws, size_t ws_size,
                              hipStream_t stream) {
  const float* x  = (const float*)d_in[0];
  const float* Wq = (const float*)d_in[1];
  const float* bq = (const float*)d_in[2];
  const float* Wk = (const float*)d_in[3];
  const float* bk = (const float*)d_in[4];
  const float* Wv = (const float*)d_in[5];
  const float* bv = (const float*)d_in[6];
  const float* Wo = (const float*)d_in[7];
  const float* bo = (const float*)d_in[8];

  const size_t MD = (size_t)M_DIM * D_DIM;   // 33,554,432 elems
  const size_t DD = (size_t)D_DIM * D_DIM;   //  4,194,304 elems

  unsigned short* xb   = (unsigned short*)d_ws;
  unsigned short* Wt   = xb + MD;
  unsigned short* qkvb = Wt + 4 * DD;
  const size_t need_bytes = (MD + 4 * DD + 3 * MD) * sizeof(unsigned short);
  if (ws_size < need_bytes) return;

  // 1) x -> bf16
  cvt_x_kernel<<<2048, 256, 0, stream>>>((const float4*)x, xb, (int)(MD / 4));

  // 2) weights -> bf16 transposed [N][K]
  dim3 tb(32, 8), tg(64, 64);
  cvt_wt_kernel<<<tg, tb, 0, stream>>>(Wq, Wt + 0 * DD);
  cvt_wt_kernel<<<tg, tb, 0, stream>>>(Wk, Wt + 1 * DD);
  cvt_wt_kernel<<<tg, tb, 0, stream>>>(Wv, Wt + 2 * DD);
  cvt_wt_kernel<<<tg, tb, 0, stream>>>(Wo, Wt + 3 * DD);

  // 3) fused QKV GEMM: [16384,2048] @ [2048,6144]^T -> q|k|v bf16 planes
  gemm256_kernel<true><<<64 * 24, 512, 0, stream>>>(xb, Wt, bq, bk, bv, qkvb);

  // 4) per-token head attention -> attn bf16 (reuses xb)
  attn_kernel<<<4096, 256, 0, stream>>>(qkvb, xb);

  // 5) output GEMM: attn @ Wo + bo -> fp32
  gemm256_kernel<false><<<64 * 8, 512, 0, stream>>>(xb, Wt + 3 * DD, bo, nullptr, nullptr, d_out);
}